// Round 10
// baseline (897.587 us; speedup 1.0000x reference)
//
#include <hip/hip_runtime.h>
#include <hip/hip_bf16.h>

// ---------------------------------------------------------------------------
// TokenPoseWithShiftedWindow — bf16 MFMA, round 10.
// dc2_k restructured: 256 blocks (1/CU), ijk-loop inside, A staged once
// full-K, continuous 48-tile B pipeline, contract H2 in dead B buffer.
// ---------------------------------------------------------------------------

typedef unsigned short u16;
typedef __bf16 bf16x8 __attribute__((ext_vector_type(8)));
typedef float f32x4 __attribute__((ext_vector_type(4)));

__device__ __forceinline__ u16 f2bf(float f) {
  unsigned u = __builtin_bit_cast(unsigned, f);
  return (u16)((u + 0x7FFFu + ((u >> 16) & 1u)) >> 16);
}
__device__ __forceinline__ float bf2f(u16 b) {
  unsigned u = ((unsigned)b) << 16;
  return __builtin_bit_cast(float, u);
}

#define GLOAD_LDS16(g, l)                                                      \
  __builtin_amdgcn_global_load_lds(                                            \
      (const __attribute__((address_space(1))) unsigned int*)(const void*)(g), \
      (__attribute__((address_space(3))) unsigned int*)(void*)(l), 16, 0, 0)

struct MmP {
  const u16* A;   // bf16 [M][K], row stride lda
  const u16* Bt;  // bf16 [N][K], row stride ldb (B transposed)
  const float* bias;
  void* C;
  void* aux;      // MODE 7: vT output
  const float* e1; const float* e2; const float* e3; const float* e4;
  int K, ZH, lda, ldb, ldc;
  long aSb, aSh, bSb, bSh, cSb, cSh;
};

// MODE: 0 = bf16 store (+bias)            (qkv swin, attn-out)
//       1 = f32 +bias +pos_emb            (patch embed -> tok)
//       2 = f32 residual += (+bias)       (proj, ffn2 -> tok)
//       3 = bf16 relu(+bias)              (ffn1 -> ffnh)
//       5 = bf16 bn-relu deconv1 scatter  (-> y1 token-major)
//       7 = bf16 store + vT scatter       (qkv dense)
template<int MODE, int BM>
__global__ __launch_bounds__(256) void mfma_gemm(MmP p) {
  const int z = blockIdx.z;
  const int zb = z / p.ZH, zh = z - zb * p.ZH;
  const u16* A  = p.A  + zb * p.aSb + zh * p.aSh;
  const u16* Bt = p.Bt + zb * p.bSb + zh * p.bSh;
  const int m0 = blockIdx.y * BM, n0 = blockIdx.x * 64;

  __shared__ u16 As[2][BM * 64];
  __shared__ u16 Bs[2][64 * 64];

  const int tid = threadIdx.x;
  const int wid = tid >> 6, lane = tid & 63;
  constexpr int MI = BM / 32;
  const int wm = (wid >> 1) * (BM / 2), wn = (wid & 1) * 32;
  const int lr = lane & 15, lg = lane >> 4;
  constexpr int ACH = BM / 32;

  f32x4 acc[MI][2];
  #pragma unroll
  for (int i = 0; i < MI; i++)
    #pragma unroll
    for (int j = 0; j < 2; j++) acc[i][j] = (f32x4){0.f, 0.f, 0.f, 0.f};

  auto stage = [&](int buf, int kt) {
    #pragma unroll
    for (int i = 0; i < ACH; i++) {
      int c = i * 256 + tid;
      int row = c >> 3, cc = c & 7;
      int gk = ((cc ^ (row & 7)) << 3) + (kt << 6);
      GLOAD_LDS16(A + (long)(m0 + row) * p.lda + gk, As[buf] + c * 8);
    }
    #pragma unroll
    for (int i = 0; i < 2; i++) {
      int c = i * 256 + tid;
      int row = c >> 3, cc = c & 7;
      int gk = ((cc ^ (row & 7)) << 3) + (kt << 6);
      GLOAD_LDS16(Bt + (long)(n0 + row) * p.ldb + gk, Bs[buf] + c * 8);
    }
  };

  const int nKT = p.K >> 6;
  stage(0, 0);
  asm volatile("s_waitcnt vmcnt(0)");
  __syncthreads();

  int cur = 0;
  for (int kt = 0; kt < nKT; ++kt) {
    const bool more = (kt + 1 < nKT);
    if (more) stage(cur ^ 1, kt + 1);

    bf16x8 af[MI][2], bfr[2][2];
    #pragma unroll
    for (int i = 0; i < MI; i++)
      #pragma unroll
      for (int ks = 0; ks < 2; ks++) {
        int row = wm + i * 16 + lr;
        int j = ks * 4 + lg;
        af[i][ks] = *(const bf16x8*)(As[cur] + (row * 8 + (j ^ (row & 7))) * 8);
      }
    #pragma unroll
    for (int jn = 0; jn < 2; jn++)
      #pragma unroll
      for (int ks = 0; ks < 2; ks++) {
        int row = wn + jn * 16 + lr;
        int j = ks * 4 + lg;
        bfr[jn][ks] = *(const bf16x8*)(Bs[cur] + (row * 8 + (j ^ (row & 7))) * 8);
      }
    #pragma unroll
    for (int i = 0; i < MI; i++)
      #pragma unroll
      for (int jn = 0; jn < 2; jn++)
        #pragma unroll
        for (int ks = 0; ks < 2; ks++)
          acc[i][jn] = __builtin_amdgcn_mfma_f32_16x16x32_bf16(
              af[i][ks], bfr[jn][ks], acc[i][jn], 0, 0, 0);

    if (more) {
      asm volatile("s_waitcnt vmcnt(0)");
      __syncthreads();
      cur ^= 1;
    }
  }

  // epilogue; C/D layout: col = lane&15, row = (lane>>4)*4 + r
  const long coff = zb * p.cSb + zh * p.cSh;
  #pragma unroll
  for (int i = 0; i < MI; i++) {
    const int rowb = m0 + wm + i * 16 + lg * 4;
    #pragma unroll
    for (int jn = 0; jn < 2; jn++) {
      const int col = n0 + wn + jn * 16 + lr;
      const float bv = p.bias ? p.bias[col] : 0.f;
      #pragma unroll
      for (int r = 0; r < 4; r++) {
        const int row = rowb + r;
        const float v = acc[i][jn][r];
        if constexpr (MODE == 0) {
          ((u16*)p.C)[coff + (long)row * p.ldc + col] = f2bf(v + bv);
        } else if constexpr (MODE == 1) {
          ((float*)p.C)[coff + (long)row * p.ldc + col] =
              v + bv + p.e1[(long)(row & 511) * 384 + col];
        } else if constexpr (MODE == 2) {
          ((float*)p.C)[coff + (long)row * p.ldc + col] += v + bv;
        } else if constexpr (MODE == 3) {
          ((u16*)p.C)[coff + (long)row * p.ldc + col] = f2bf(fmaxf(v + bv, 0.f));
        } else if constexpr (MODE == 5) {
          float raw = v + bv;
          float val = fmaxf((raw - p.e3[col]) * rsqrtf(p.e4[col] + 1e-5f) * p.e1[col] + p.e2[col], 0.f);
          int b = row >> 9, hwd = row & 511;
          int h = hwd >> 6, w = (hwd >> 3) & 7, d = hwd & 7;
          int i_ = zh >> 2, j_ = (zh >> 1) & 1, k_ = zh & 1;
          long tokn = (long)b * 4096 + (2 * h + i_) * 256 + (2 * w + j_) * 16 + (2 * d + k_);
          ((u16*)p.C)[tokn * 384 + col] = f2bf(val);
        } else if constexpr (MODE == 7) {
          u16 bv16 = f2bf(v);
          ((u16*)p.C)[coff + (long)row * p.ldc + col] = bv16;
          if (col >= 768) {  // scatter V into vT [b*6+h][64][512]
            int bb = row >> 9, tt = row & 511;
            int hh = (col - 768) >> 6, dd = col & 63;
            ((u16*)p.aux)[(((long)bb * 6 + hh) << 15) + (dd << 9) + tt] = bv16;
          }
        }
      }
    }
  }
}

// Fused deconv2 + bn2 + relu + MFMA out_w contraction, ijk-loop inside.
// grid 256 (1 block/CU): block = 64-row m-tile of y1 [16384][384].
// A staged once full-K (48 KB); B double-buffered per (ijk,kt); H2 reuses
// the dead B buffer with XOR-chunk layout ([64][48 chunks of 8] = 48 KB).
__global__ __launch_bounds__(512) void dc2_k(const u16* __restrict__ y1, const u16* __restrict__ wd2,
                                             const float* __restrict__ d2b,
                                             const float* __restrict__ g, const float* __restrict__ bta,
                                             const float* __restrict__ mu, const float* __restrict__ var,
                                             const u16* __restrict__ owT, const float* __restrict__ ob,
                                             float* __restrict__ out) {
  __shared__ char smem[147456];            // 144 KB
  u16* Afull = (u16*)smem;                 // [6 kt][512 chunks][8] = 48 KB
  u16* Bb = (u16*)(smem + 49152);          // 2 x 48 KB buffers

  const int m0 = blockIdx.x * 64;
  const int tid = threadIdx.x;
  const int wid = tid >> 6, lane = tid & 63;
  const int wr = wid >> 2, wc = wid & 3;   // 2 x 4 wave grid; wave tile 32x96
  const int lr = lane & 15, lg = lane >> 4;

  auto stageB = [&](int buf, int ijk, int kt) {
    const u16* Bt = wd2 + (long)ijk * 147456;
    #pragma unroll
    for (int i = 0; i < 6; i++) {
      int c = i * 512 + tid;
      int row = c >> 3, cc = c & 7;
      int gk = ((cc ^ (row & 7)) << 3) + (kt << 6);
      GLOAD_LDS16(Bt + (long)row * 384 + gk, Bb + buf * 24576 + c * 8);
    }
  };

  // prologue: A full-K (6 slices) + first B tile
  #pragma unroll
  for (int i = 0; i < 6; i++) {
    int c = tid;
    int row = c >> 3, cc = c & 7;
    int gk = ((cc ^ (row & 7)) << 3) + (i << 6);
    GLOAD_LDS16(y1 + (long)(m0 + row) * 384 + gk, Afull + i * 4096 + c * 8);
  }
  stageB(0, 0, 0);
  asm volatile("s_waitcnt vmcnt(0)");
  __syncthreads();

  int cur = 0;
  for (int ijk = 0; ijk < 8; ++ijk) {
    f32x4 acc[2][6];
    #pragma unroll
    for (int i = 0; i < 2; i++)
      #pragma unroll
      for (int j = 0; j < 6; j++) acc[i][j] = (f32x4){0.f, 0.f, 0.f, 0.f};

    for (int kt = 0; kt < 6; ++kt) {
      const bool more = (kt < 5);
      if (more) stageB(cur ^ 1, ijk, kt + 1);
      bf16x8 af[2][2], bfr[6][2];
      #pragma unroll
      for (int i = 0; i < 2; i++)
        #pragma unroll
        for (int ks = 0; ks < 2; ks++) {
          int row = wr * 32 + i * 16 + lr;
          int j = ks * 4 + lg;
          af[i][ks] = *(const bf16x8*)(Afull + kt * 4096 + (row * 8 + (j ^ (row & 7))) * 8);
        }
      #pragma unroll
      for (int jn = 0; jn < 6; jn++)
        #pragma unroll
        for (int ks = 0; ks < 2; ks++) {
          int row = wc * 96 + jn * 16 + lr;
          int j = ks * 4 + lg;
          bfr[jn][ks] = *(const bf16x8*)(Bb + cur * 24576 + (row * 8 + (j ^ (row & 7))) * 8);
        }
      #pragma unroll
      for (int i = 0; i < 2; i++)
        #pragma unroll
        for (int jn = 0; jn < 6; jn++)
          #pragma unroll
          for (int ks = 0; ks < 2; ks++)
            acc[i][jn] = __builtin_amdgcn_mfma_f32_16x16x32_bf16(
                af[i][ks], bfr[jn][ks], acc[i][jn], 0, 0, 0);
      if (more) {
        asm volatile("s_waitcnt vmcnt(0)");
        __syncthreads();
        cur ^= 1;
      }
    }
    __syncthreads();  // all MFMA reads of Bb[cur] done; acc final

    // bn2+relu -> H2 in the dead buffer (cur^1); prefetch next ijk kt0 -> cur
    u16* hbuf = Bb + (cur ^ 1) * 24576;
    #pragma unroll
    for (int i = 0; i < 2; i++)
      #pragma unroll
      for (int jn = 0; jn < 6; jn++) {
        const int col = wc * 96 + jn * 16 + lr;
        const int cc = col >> 3, e = col & 7;
        const float scale = rsqrtf(var[col] + 1e-5f) * g[col];
        const float bias2 = bta[col] - mu[col] * scale;
        const float db = d2b[col];
        #pragma unroll
        for (int r = 0; r < 4; r++) {
          int row = wr * 32 + i * 16 + lg * 4 + r;
          float val = fmaxf((acc[i][jn][r] + db) * scale + bias2, 0.f);
          hbuf[row * 384 + ((cc ^ (row & 7)) << 3) + e] = f2bf(val);
        }
      }
    if (ijk < 7) stageB(cur, ijk + 1, 0);
    __syncthreads();  // H2 complete

    // MFMA contraction: waves 0-3; wave w rows [w*16, w*16+16) x owT[16][384]
    if (wid < 4) {
      f32x4 c4 = (f32x4){0.f, 0.f, 0.f, 0.f};
      const int row = wid * 16 + lr;
      #pragma unroll
      for (int mf = 0; mf < 12; mf++) {
        int j = mf * 4 + lg;
        bf16x8 af = *(const bf16x8*)(hbuf + row * 384 + ((j ^ (row & 7)) << 3));
        bf16x8 bf = *(const bf16x8*)(owT + lr * 384 + j * 8);
        c4 = __builtin_amdgcn_mfma_f32_16x16x32_bf16(af, bf, c4, 0, 0, 0);
      }
      if (lr < 15) {
        const int i_ = ijk >> 2, j_ = (ijk >> 1) & 1, k_ = ijk & 1;
        const float bkp = ob[lr];
        #pragma unroll
        for (int r = 0; r < 4; r++) {
          const int gm = m0 + wid * 16 + lg * 4 + r;
          const int b = gm >> 12, h = (gm >> 8) & 15, w = (gm >> 4) & 15, d = gm & 15;
          const long o = ((long)(b * 15 + lr) << 15) + (2 * h + i_) * 1024 + (2 * w + j_) * 32 + (2 * d + k_);
          out[o] = c4[r] + bkp;
        }
      }
    }
    if (ijk < 7) asm volatile("s_waitcnt vmcnt(0)");
    __syncthreads();  // kt0 ready in cur; hbuf free for next kt1
  }
}

// Fused scores+softmax: P = softmax(Q K^T / 8) per (b,h). One block per
// (q-tile of 64, bh); 256 threads (4 waves x 16 q-rows); K in swizzled LDS.
__global__ __launch_bounds__(256) void attnsm_k(const u16* __restrict__ qkv, u16* __restrict__ P) {
  const int bh = blockIdx.y;
  const int b = bh / 6, h = bh - b * 6;
  const int qt = blockIdx.x;
  const int tid = threadIdx.x, wid = tid >> 6, lane = tid & 63;
  const int lr = lane & 15, lg = lane >> 4;
  __shared__ u16 Ks[512 * 64];
  const u16* qbase = qkv + ((long)b * 512) * 1152 + h * 64;

  #pragma unroll
  for (int i = 0; i < 16; i++) {
    int c = i * 256 + tid;
    int t = c >> 3, cc = c & 7;
    int gk = (cc ^ (t & 7)) << 3;
    GLOAD_LDS16(qbase + (long)t * 1152 + 384 + gk, Ks + c * 8);
  }
  const int qrow = qt * 64 + wid * 16 + lr;
  bf16x8 qf[2];
  #pragma unroll
  for (int ks = 0; ks < 2; ks++)
    qf[ks] = *(const bf16x8*)(qbase + (long)qrow * 1152 + (ks * 4 + lg) * 8);
  asm volatile("s_waitcnt vmcnt(0)");
  __syncthreads();

  f32x4 s[32];
  #pragma unroll
  for (int nt = 0; nt < 32; nt++) {
    s[nt] = (f32x4){0.f, 0.f, 0.f, 0.f};
    #pragma unroll
    for (int ks = 0; ks < 2; ks++) {
      int row = nt * 16 + lr;
      int j = ks * 4 + lg;
      bf16x8 kf = *(const bf16x8*)(Ks + (row * 8 + (j ^ (row & 7))) * 8);
      s[nt] = __builtin_amdgcn_mfma_f32_16x16x32_bf16(qf[ks], kf, s[nt], 0, 0, 0);
    }
  }
  float mx[4] = {-1e30f, -1e30f, -1e30f, -1e30f};
  #pragma unroll
  for (int nt = 0; nt < 32; nt++)
    #pragma unroll
    for (int r = 0; r < 4; r++) { s[nt][r] *= 0.125f; mx[r] = fmaxf(mx[r], s[nt][r]); }
  #pragma unroll
  for (int o = 8; o >= 1; o >>= 1)
    #pragma unroll
    for (int r = 0; r < 4; r++) mx[r] = fmaxf(mx[r], __shfl_xor(mx[r], o));
  float sum[4] = {0.f, 0.f, 0.f, 0.f};
  #pragma unroll
  for (int nt = 0; nt < 32; nt++)
    #pragma unroll
    for (int r = 0; r < 4; r++) { float e = __expf(s[nt][r] - mx[r]); s[nt][r] = e; sum[r] += e; }
  #pragma unroll
  for (int o = 8; o >= 1; o >>= 1)
    #pragma unroll
    for (int r = 0; r < 4; r++) sum[r] += __shfl_xor(sum[r], o);
  float inv[4];
  #pragma unroll
  for (int r = 0; r < 4; r++) inv[r] = 1.f / sum[r];

  u16* Pb = P + (long)bh * 262144;
  const int prow0 = qt * 64 + wid * 16 + lg * 4;
  #pragma unroll
  for (int nt = 0; nt < 32; nt++)
    #pragma unroll
    for (int r = 0; r < 4; r++)
      Pb[(long)(prow0 + r) * 512 + nt * 16 + lr] = f2bf(s[nt][r] * inv[r]);
}

// ---------------- aux kernels ----------------

__global__ __launch_bounds__(256) void ln_k(const float* __restrict__ x, const float* __restrict__ g,
                                            const float* __restrict__ b, u16* __restrict__ y) {
  const int row = (blockIdx.x << 2) + (threadIdx.x >> 6);
  const int lane = threadIdx.x & 63;
  const float* xr = x + (long)row * 384;
  float v[6]; float s = 0.f;
  #pragma unroll
  for (int i = 0; i < 6; i++) { v[i] = xr[lane + (i << 6)]; s += v[i]; }
  #pragma unroll
  for (int o = 32; o >= 1; o >>= 1) s += __shfl_xor(s, o);
  const float mean = s * (1.f / 384.f);
  float q = 0.f;
  #pragma unroll
  for (int i = 0; i < 6; i++) { float dd = v[i] - mean; q += dd * dd; }
  #pragma unroll
  for (int o = 32; o >= 1; o >>= 1) q += __shfl_xor(q, o);
  const float rstd = rsqrtf(q * (1.f / 384.f) + 1e-5f);
  u16* yr = y + (long)row * 384;
  #pragma unroll
  for (int i = 0; i < 6; i++) {
    int c = lane + (i << 6);
    yr[c] = f2bf((v[i] - mean) * rstd * g[c] + b[c]);
  }
}

__global__ __launch_bounds__(64) void swin_k(const u16* __restrict__ qkv, u16* __restrict__ attno) {
  const int blk = blockIdx.x;
  const int h = blk % 6; const int bw = blk / 6;
  const int b = bw >> 6, win = bw & 63;
  const int wh = win >> 4, ww = (win >> 2) & 3, wd = win & 3;
  const int lane = threadIdx.x;
  __shared__ float qs[8][68], ks[8][68], vs[8][68], attw[8][8];
  __shared__ int ntok[8];
  if (lane < 8) {
    int i = lane >> 2, j = (lane >> 1) & 1, k = lane & 1;
    int oh = (2 * wh + i + 1) & 7, ow = (2 * ww + j + 1) & 7, od = (2 * wd + k + 1) & 7;
    ntok[lane] = oh * 64 + ow * 8 + od;
  }
  __syncthreads();
  #pragma unroll
  for (int t = 0; t < 8; t++) {
    long base = ((long)b * 512 + ntok[t]) * 1152 + h * 64 + lane;
    qs[t][lane] = bf2f(qkv[base]);
    ks[t][lane] = bf2f(qkv[base + 384]);
    vs[t][lane] = bf2f(qkv[base + 768]);
  }
  __syncthreads();
  const int tq = lane >> 3, tm = lane & 7;
  float sc = 0.f;
  #pragma unroll 16
  for (int d = 0; d < 64; d++) sc += qs[tq][d] * ks[tm][d];
  sc *= 0.125f;
  float mx = sc;
  mx = fmaxf(mx, __shfl_xor(mx, 4));
  mx = fmaxf(mx, __shfl_xor(mx, 2));
  mx = fmaxf(mx, __shfl_xor(mx, 1));
  float e = __expf(sc - mx);
  float sm = e;
  sm += __shfl_xor(sm, 4); sm += __shfl_xor(sm, 2); sm += __shfl_xor(sm, 1);
  attw[tq][tm] = e / sm;
  __syncthreads();
  #pragma unroll
  for (int t = 0; t < 8; t++) {
    float o = 0.f;
    #pragma unroll
    for (int m = 0; m < 8; m++) o += attw[t][m] * vs[m][lane];
    attno[((long)b * 512 + ntok[t]) * 384 + h * 64 + lane] = f2bf(o);
  }
}

__global__ __launch_bounds__(256) void im2col_k(const float* __restrict__ x, u16* __restrict__ xp) {
  const int i = blockIdx.x * 256 + threadIdx.x;
  const int l = i & 511; const int m = i >> 9;
  const int b = m >> 9, n = m & 511;
  const int h = n >> 6, w = (n >> 3) & 7, d = n & 7;
  const int pi = l >> 6, pj = (l >> 3) & 7, pk = l & 7;
  xp[i] = f2bf(x[(long)b * 262144 + (long)(h * 8 + pi) * 4096 + (w * 8 + pj) * 64 + (d * 8 + pk)]);
}

__global__ __launch_bounds__(256) void castw_k(const float* __restrict__ in, u16* __restrict__ out, int n) {
  for (int i = blockIdx.x * 256 + threadIdx.x; i < n; i += gridDim.x * 256)
    out[i] = f2bf(in[i]);
}

// LDS-tiled transpose+cast for the 7 [z=4][K][N] weights -> [z][N][K] bf16.
struct TJ { const float* s[7]; u16* d[7]; };
__global__ __launch_bounds__(256) void transpose_tiled_k(TJ tj) {
  __shared__ u16 tile[64][65];
  const int cumt[8] = {0, 432, 576, 720, 1296, 1872, 2448, 3024};
  const int bi = blockIdx.x;
  int j = 0;
  #pragma unroll
  for (int t = 1; t < 7; t++) if (bi >= cumt[t]) j = t;
  const int li = bi - cumt[j];
  const int Kj = (j >= 5) ? 1536 : 384;
  const int Nj = (j == 0) ? 1152 : ((j == 3 || j == 4) ? 1536 : 384);
  const int tn_cnt = Nj >> 6;
  const int per_z = (Kj >> 6) * tn_cnt;
  const int z = li / per_z;
  int rem = li - z * per_z;
  const int tk = rem / tn_cnt, tn = rem - tk * tn_cnt;
  const float* src = tj.s[j] + (long)z * Kj * Nj;
  u16* dst = tj.d[j] + (long)z * Kj * Nj;
  const int k0 = tk << 6, n0 = tn << 6;
  const int rl = threadIdx.x >> 6, c = threadIdx.x & 63;
  #pragma unroll
  for (int i = 0; i < 16; i++) {
    int r = i * 4 + rl;
    tile[r][c] = f2bf(src[(long)(k0 + r) * Nj + n0 + c]);
  }
  __syncthreads();
  #pragma unroll
  for (int i = 0; i < 16; i++) {
    int n = i * 4 + rl;
    dst[(long)(n0 + n) * Kj + k0 + c] = tile[c][n];
  }
}

// dense per-head qkv weights -> [4][1152][384] bf16, LDS-tiled. 432 blocks.
__global__ __launch_bounds__(256) void repack_mqkv_k2(const float* __restrict__ qw, const float* __restrict__ kw,
                                                      const float* __restrict__ vw, u16* __restrict__ out) {
  __shared__ u16 tile[64][65];
  const int bi = blockIdx.x;
  const int j = bi / 108;
  int rem = bi - j * 108;
  const int s = rem / 36; rem -= s * 36;
  const int h = rem / 6, tk = rem - h * 6;
  const float* src = (s == 0 ? qw : s == 1 ? kw : vw) + (long)j * 147456;
  const int rl = threadIdx.x >> 6, cc = threadIdx.x & 63;
  #pragma unroll
  for (int i = 0; i < 16; i++) {
    int cl = tk * 64 + i * 4 + rl;
    tile[i * 4 + rl][cc] = f2bf(src[(long)(h * 384 + cl) * 64 + cc]);
  }
  __syncthreads();
  u16* ob = out + (long)j * 442368 + (long)(s * 384 + h * 64) * 384 + tk * 64;
  #pragma unroll
  for (int i = 0; i < 16; i++) {
    int d = i * 4 + rl;
    ob[(long)d * 384 + cc] = tile[cc][d];
  }
}

// both deconv weights -> [8][O][C] bf16 (blocks 0..143) + owT repack (block 144).
__global__ __launch_bounds__(256) void repack_dw2_k(const float* __restrict__ in1, u16* __restrict__ out1,
                                                    const float* __restrict__ in2, u16* __restrict__ out2,
                                                    const float* __restrict__ ow, u16* __restrict__ owT) {
  if (blockIdx.x >= 144) {
    for (int i = threadIdx.x; i < 6144; i += 256)
      owT[i] = (i < 5760) ? f2bf(ow[i]) : (u16)0;
    return;
  }
  __shared__ u16 ds[32][514];
  const int sel = blockIdx.x >= 72;
  const float* in = sel ? in2 : in1;
  u16* out = sel ? out2 : out1;
  const int bx = sel ? blockIdx.x - 72 : blockIdx.x;
  const int bo = bx % 6, bc = bx / 6;
  const int c0 = bc * 32, o0 = bo * 64;
  #pragma unroll 4
  for (int it = 0; it < 64; it++) {
    int fl = it * 256 + threadIdx.x;
    int cr = fl >> 9, mm = fl & 511;
    ds[cr][mm] = f2bf(in[(long)(c0 + cr) * 3072 + o0 * 8 + mm]);
  }
  __syncthreads();
  #pragma unroll 4
  for (int it = 0; it < 64; it++) {
    int fl = it * 256 + threadIdx.x;
    int ijk = fl >> 11, rem = fl & 2047;
    int oo = rem >> 5, cr = rem & 31;
    out[(long)ijk * 147456 + (long)(o0 + oo) * 384 + c0 + cr] = ds[cr][oo * 8 + ijk];
  }
}

// ---------------------------------------------------------------------------

static MmP mk(const u16* A, const u16* Bt, const float* bias, void* C,
              int K, int lda, int ldb, int ldc) {
  MmP p{};
  p.A = A; p.Bt = Bt; p.bias = bias; p.C = C; p.aux = nullptr;
  p.e1 = p.e2 = p.e3 = p.e4 = nullptr;
  p.K = K; p.ZH = 1; p.lda = lda; p.ldb = ldb; p.ldc = ldc;
  p.aSb = p.aSh = p.bSb = p.bSh = p.cSb = p.cSh = 0;
  return p;
}

extern "C" void kernel_launch(void* const* d_in, const int* in_sizes, int n_in,
                              void* d_out, int out_size, void* d_ws, size_t ws_size,
                              hipStream_t stream) {
  (void)in_sizes; (void)n_in; (void)out_size; (void)ws_size;
  const float* x        = (const float*)d_in[0];
  const float* patch_w  = (const float*)d_in[1];
  const float* patch_b  = (const float*)d_in[2];
  const float* pos_emb  = (const float*)d_in[3];
  const float* m_ln1_g  = (const float*)d_in[4];
  const float* m_ln1_b  = (const float*)d_in[5];
  const float* m_qw     = (const float*)d_in[6];
  const float* m_kw     = (const float*)d_in[7];
  const float* m_vw     = (const float*)d_in[8];
  const float* m_proj_w = (const float*)d_in[9];
  const float* m_proj_b = (const float*)d_in[10];
  const float* m_ln2_g  = (const float*)d_in[11];
  const float* m_ln2_b  = (const float*)d_in[12];
  const float* m_w1     = (const float*)d_in[13];
  const float* m_b1     = (const float*)d_in[14];
  const float* m_w2     = (const float*)d_in[15];
  const float* m_b2     = (const float*)d_in[16];
  const float* s_ln1_g  = (const float*)d_in[17];
  const float* s_ln1_b  = (const float*)d_in[18];
  const float* s_qkv_w  = (const float*)d_in[19];
  const float* s_qkv_b  = (const float*)d_in[20];
  const float* s_proj_w = (const float*)d_in[21];
  const float* s_proj_b = (const float*)d_in[22];
  const float* s_ln2_g  = (const float*)d_in[23];
  const float* s_ln2_b  = (const float*)d_in[24];
  const float* s_w1     = (const float*)d_in[25];
  const float* s_b1     = (const float*)d_in[26];
  const float* s_w2     = (const float*)d_in[27];
  const float* s_b2     = (const float*)d_in[28];
  const float* d1_w     = (const float*)d_in[29];
  const float* d1_b     = (const float*)d_in[30];
  const float* bn1_g    = (const float*)d_in[31];
  const float* bn1_b    = (const float*)d_in[32];
  const float* bn1_m    = (const float*)d_in[33];
  const float* bn1_v    = (const float*)d_in[34];
  const float* d2_w     = (const float*)d_in[35];
  const float* d2_b     = (const float*)d_in[36];
  const float* bn2_g    = (const float*)d_in[37];
  const float* bn2_b    = (const float*)d_in[38];
  const float* bn2_m    = (const float*)d_in[39];
  const float* bn2_v    = (const float*)d_in[40];
  const float* out_w    = (const float*)d_in[41];
  const float* out_b    = (const float*)d_in[42];
  float* out = (float*)d_out;

  // ---- workspace arena ----
  char* wsp = (char*)d_ws;
  auto alloc = [&](size_t bytes) { void* p = wsp; wsp += (bytes + 255) & ~(size_t)255; return p; };
  float* tok    = (float*)alloc(786432 * 4);
  u16* wqkv_m   = (u16*)alloc(1769472 * 2);
  u16* wqkv_s   = (u16*)alloc(1769472 * 2);
  u16* wproj_m  = (u16*)alloc(589824 * 2);
  u16* wproj_s  = (u16*)alloc(589824 * 2);
  u16* w1m      = (u16*)alloc(2359296 * 2);
  u16* w1s      = (u16*)alloc(2359296 * 2);
  u16* w2m      = (u16*)alloc(2359296 * 2);
  u16* w2s      = (u16*)alloc(2359296 * 2);
  u16* wpatch   = (u16*)alloc(196608 * 2);
  u16* wd1      = (u16*)alloc(1179648 * 2);
  u16* wd2      = (u16*)alloc(1179648 * 2);
  u16* owT      = (u16*)alloc(6144 * 2);
  u16* lnb      = (u16*)alloc(786432 * 2);
  u16* qkvb     = (u16*)alloc(2359296 * 2);
  u16* attnob   = (u16*)alloc(786432 * 2);
  u16* ffnhb    = (u16*)alloc(3145728 * 2);
  u16* scoresb  = (u16*)alloc(6291456 * 2);   // 24x512x512; aliased by xp / y1b
  u16* vTb      = (u16*)alloc(786432 * 2);    // aliased by tokb (late)
  u16* xpb   = scoresb;
  u16* y1b   = scoresb;
  u16* tokb  = vTb;

  // ---- weight repack (all LDS-tiled, coalesced) ----
  castw_k<<<256, 256, 0, stream>>>(patch_w, wpatch, 196608);
  repack_mqkv_k2<<<432, 256, 0, stream>>>(m_qw, m_kw, m_vw, wqkv_m);
  {
    TJ tj;
    tj.s[0] = s_qkv_w;  tj.d[0] = wqkv_s;
    tj.s[1] = m_proj_w; tj.d[1] = wproj_m;
    tj.s[2] = s_proj_w; tj.d[2] = wproj_s;
    tj.s[3] = m_w1;     tj.d[3] = w1m;
    tj.s[4] = s_w1;     tj.d[4] = w1s;
    tj.s[5] = m_w2;     tj.d[5] = w2m;
    tj.s[6] = s_w2;     tj.d[6] = w2s;
    transpose_tiled_k<<<3024, 256, 0, stream>>>(tj);
  }
  repack_dw2_k<<<145, 256, 0, stream>>>(d1_w, wd1, d2_w, wd2, out_w, owT);

  // ---- patch embedding + pos_emb -> tok (fp32) ----
  im2col_k<<<4096, 256, 0, stream>>>(x, xpb);
  {
    MmP p = mk(xpb, wpatch, patch_b, tok, 512, 512, 512, 384);
    p.e1 = pos_emb;
    mfma_gemm<1, 64><<<dim3(6, 32, 1), 256, 0, stream>>>(p);
  }

  for (int j = 0; j < 4; j++) {
    // ======== dense block ========
    ln_k<<<512, 256, 0, stream>>>(tok, m_ln1_g + j * 384, m_ln1_b + j * 384, lnb);
    {  // QKV (no bias) + fused vT scatter
      MmP p = mk(lnb, wqkv_m + (long)j * 442368, nullptr, qkvb, 384, 384, 384, 1152);
      p.aux = vTb;
      mfma_gemm<7, 128><<<dim3(18, 16, 1), 256, 0, stream>>>(p);
    }
    attnsm_k<<<dim3(8, 24, 1), 256, 0, stream>>>(qkvb, scoresb);
    {  // attno = P V per (b,h): M=512 N=64 K=512
      MmP p = mk(scoresb, vTb, nullptr, attnob, 512, 512, 512, 384);
      p.ZH = 6; p.aSb = 1572864; p.aSh = 262144; p.bSb = 196608; p.bSh = 32768;
      p.cSb = 196608; p.cSh = 64;
      mfma_gemm<0, 64><<<dim3(1, 8, 24), 256, 0, stream>>>(p);
    }
    {  // proj + residual -> tok fp32
      MmP p = mk(attnob, wproj_m + (long)j * 147456, m_proj_b + j * 384, tok, 384, 384, 384, 384);
      mfma_gemm<2, 64><<<dim3(6, 32, 1), 256, 0, stream>>>(p);
    }
    ln_k<<<512, 256, 0, stream>>>(tok, m_ln2_g + j * 384, m_ln2_b + j * 384, lnb);
    {  // FFN1 relu
      MmP p = mk(lnb, w1m + (long)j * 589824, m_b1 + j * 1536, ffnhb, 384, 384, 384, 1536);
      mfma_gemm<3, 128><<<dim3(24, 16, 1), 256, 0, stream>>>(p);
    }
    {  // FFN2 + residual
      MmP p = mk(ffnhb, w2m + (long)j * 589824, m_b2 + j * 384, tok, 1536, 1536, 1536, 384);
      mfma_gemm<2, 64><<<dim3(6, 32, 1), 256, 0, stream>>>(p);
    }

    // ======== shifted-window block ========
    ln_k<<<512, 256, 0, stream>>>(tok, s_ln1_g + j * 384, s_ln1_b + j * 384, lnb);
    {
      MmP p = mk(lnb, wqkv_s + (long)j * 442368, s_qkv_b + j * 1152, qkvb, 384, 384, 384, 1152);
      mfma_gemm<0, 128><<<dim3(18, 16, 1), 256, 0, stream>>>(p);
    }
    swin_k<<<1536, 64, 0, stream>>>(qkvb, attnob);
    {
      MmP p = mk(attnob, wproj_s + (long)j * 147456, s_proj_b + j * 384, tok, 384, 384, 384, 384);
      mfma_gemm<2, 64><<<dim3(6, 32, 1), 256, 0, stream>>>(p);
    }
    ln_k<<<512, 256, 0, stream>>>(tok, s_ln2_g + j * 384, s_ln2_b + j * 384, lnb);
    {
      MmP p = mk(lnb, w1s + (long)j * 589824, s_b1 + j * 1536, ffnhb, 384, 384, 384, 1536);
      mfma_gemm<3, 128><<<dim3(24, 16, 1), 256, 0, stream>>>(p);
    }
    {
      MmP p = mk(ffnhb, w2s + (long)j * 589824, s_b2 + j * 384, tok, 1536, 1536, 1536, 384);
      mfma_gemm<2, 64><<<dim3(6, 32, 1), 256, 0, stream>>>(p);
    }
  }

  // ---- decoder ----
  castw_k<<<768, 256, 0, stream>>>(tok, tokb, 786432);
  {  // deconv1 all 8 positions + bn1-relu -> y1b token-major
    MmP p = mk(tokb, wd1, d1_b, y1b, 384, 384, 384, 384);
    p.ZH = 8; p.bSh = 147456;
    p.e1 = bn1_g; p.e2 = bn1_b; p.e3 = bn1_m; p.e4 = bn1_v;
    mfma_gemm<5, 128><<<dim3(6, 16, 8), 256, 0, stream>>>(p);
  }
  // fused deconv2 + bn2 + relu + MFMA contraction (256 blocks, ijk inside)
  dc2_k<<<256, 512, 0, stream>>>(y1b, wd2, d2_b, bn2_g, bn2_b, bn2_m, bn2_v,
                                 owT, out_b, out);
}